// Round 5
// baseline (242.232 us; speedup 1.0000x reference)
//
#include <hip/hip_runtime.h>

// ROIAlign (FPN, multi-level) for MI355X.
// Inputs (f32): fm2 [4,256,256,256] s4 | fm3 [4,128,128,256] s8
//               fm4 [4,64,64,256] s16  | fm5 [4,32,32,256] s32
//               rois [4,512,4] (x1,y1,x2,y2)
// Output (f32): [4,512,256,7,7]
//
// R4 -> R5: byte reduction via corner dedup. R3->R4 proved the kernel is
// bound by gather BYTES returned (halving load instrs at same bytes = null).
// Per bin, merge duplicate corner rows/cols (sample step < 1 makes adjacent
// samples share corners) by summing bilinear weights; skip loads whose merged
// weight == 0 via wave-uniform guards. All surviving loads issue batched
// before any FMA (MLP preserved); skipped pixels are zero so FMAs are
// unconditional (no undef speculation). Typical bin: 6-9 pixels vs 16.

constexpr int S     = 7;
constexpr int SS    = 49;
constexpr int CCH   = 256;
constexpr int NROI  = 512;
constexpr int BATCH = 4;

__global__ __launch_bounds__(512, 4) void roialign_kernel(
    const float* __restrict__ fm2, const float* __restrict__ fm3,
    const float* __restrict__ fm4, const float* __restrict__ fm5,
    const float* __restrict__ rois, float* __restrict__ out)
{
    __shared__ float    tile[SS * CCH];   // 50176 B, XOR-swizzled channel index
    __shared__ float    s_wyh[14], s_wyl[14], s_wxh[14], s_wxl[14];
    __shared__ unsigned s_ry0[14], s_ry1[14], s_cx0[14], s_cx1[14];

    const int roi = blockIdx.x;        // 0 .. B*N-1
    const int b   = roi >> 9;

    // ---- wave-uniform prologue ----
    const float x1  = rois[roi * 4 + 0];
    const float y1v = rois[roi * 4 + 1];
    const float x2  = rois[roi * 4 + 2];
    const float y2v = rois[roi * 4 + 3];

    const float area = (y2v - y1v) * (x2 - x1);
    const float lraw = logf(sqrtf(area) * (1.0f / 224.0f)) * 1.4426950408889634f + 4.0f;
    int lvl = (int)rintf(lraw);
    lvl = lvl < 2 ? 2 : (lvl > 5 ? 5 : lvl);

    const float* fm; int H; float scale;
    if (lvl == 2)      { fm = fm2; H = 256; scale = 0.25f;    }
    else if (lvl == 3) { fm = fm3; H = 128; scale = 0.125f;   }
    else if (lvl == 4) { fm = fm4; H = 64;  scale = 0.0625f;  }
    else               { fm = fm5; H = 32;  scale = 0.03125f; }
    const int W = H;
    fm += (size_t)b * H * W * CCH;

    const float bx1 = x1 * scale, by1 = y1v * scale;
    const float rw  = fmaxf(x2 * scale - bx1, 1.0f);
    const float rh  = fmaxf(y2v * scale - by1, 1.0f);
    const float stx = rw * (1.0f / 7.0f);
    const float sty = rh * (1.0f / 7.0f);

    const int t = threadIdx.x;

    // ---- sample LUT: 14 y entries (wave 0) + 14 x entries (wave 1) ----
    if (t < 14) {
        const int k = t;
        const float yy = by1 + ((float)k + 0.5f) * 0.5f * sty;
        const float Hf = (float)H;
        const bool  v  = (yy > -1.0f) && (yy < Hf);
        const float yc = fminf(fmaxf(yy, 0.0f), Hf - 1.0f);
        const int   y0 = (int)floorf(yc);
        const int   y1i = min(y0 + 1, H - 1);
        const float ly = yc - (float)y0;
        s_wyl[k] = v ? ly : 0.0f;
        s_wyh[k] = v ? 1.0f - ly : 0.0f;
        s_ry0[k] = (unsigned)(y0  * W * (CCH * 4));   // byte offset of fm row
        s_ry1[k] = (unsigned)(y1i * W * (CCH * 4));
    } else if (t >= 64 && t < 78) {
        const int k = t - 64;
        const float xx = bx1 + ((float)k + 0.5f) * 0.5f * stx;
        const float Wf = (float)W;
        const bool  v  = (xx > -1.0f) && (xx < Wf);
        const float xc = fminf(fmaxf(xx, 0.0f), Wf - 1.0f);
        const int   x0 = (int)floorf(xc);
        const int   x1i = min(x0 + 1, W - 1);
        const float lx = xc - (float)x0;
        s_wxl[k] = v ? lx : 0.0f;
        s_wxh[k] = v ? 1.0f - lx : 0.0f;
        s_cx0[k] = (unsigned)(x0  * (CCH * 4));       // byte offset of fm col
        s_cx1[k] = (unsigned)(x1i * (CCH * 4));
    }
    __syncthreads();

    // ---- compute: one bin per wave-pass, 4 channels (float4) per lane ----
    const int lane = t & 63;
    const int wv   = t >> 6;                       // 0..7
    const unsigned cb = (unsigned)(lane << 4);     // byte offset within pixel

    const char* __restrict__ fmb = (const char*)fm;
    const float4 z4 = make_float4(0.f, 0.f, 0.f, 0.f);

    for (int bin = wv; bin < SS; bin += 8) {
        const int sy = bin / 7;
        const int sx = bin - sy * 7;
        const int ky = sy << 1, kx = sx << 1;

        // --- merge duplicate corner rows (sum weights; exclusive chain) ---
        float w0 = s_wyh[ky], w1 = s_wyl[ky], w2 = s_wyh[ky + 1], w3 = s_wyl[ky + 1];
        const unsigned rA = s_ry0[ky], rB = s_ry1[ky];
        const unsigned rC = s_ry0[ky + 1], rD = s_ry1[ky + 1];
        {
            const bool eBA = (rB == rA);
            w0 += eBA ? w1 : 0.f;  w1 = eBA ? 0.f : w1;
            const bool eCA = (rC == rA);
            const bool eCB = !eCA && (rC == rB);
            w0 += eCA ? w2 : 0.f;  w1 += eCB ? w2 : 0.f;
            w2 = (eCA || eCB) ? 0.f : w2;
            const bool eDA = (rD == rA);
            const bool eDB = !eDA && (rD == rB);
            const bool eDC = !eDA && !eDB && (rD == rC);
            w0 += eDA ? w3 : 0.f;  w1 += eDB ? w3 : 0.f;  w2 += eDC ? w3 : 0.f;
            w3 = (eDA || eDB || eDC) ? 0.f : w3;
        }
        // --- merge duplicate corner cols ---
        float u0 = s_wxh[kx], u1 = s_wxl[kx], u2 = s_wxh[kx + 1], u3 = s_wxl[kx + 1];
        const unsigned cA = s_cx0[kx], cB = s_cx1[kx];
        const unsigned cC = s_cx0[kx + 1], cD = s_cx1[kx + 1];
        {
            const bool eBA = (cB == cA);
            u0 += eBA ? u1 : 0.f;  u1 = eBA ? 0.f : u1;
            const bool eCA = (cC == cA);
            const bool eCB = !eCA && (cC == cB);
            u0 += eCA ? u2 : 0.f;  u1 += eCB ? u2 : 0.f;
            u2 = (eCA || eCB) ? 0.f : u2;
            const bool eDA = (cD == cA);
            const bool eDB = !eDA && (cD == cB);
            const bool eDC = !eDA && !eDB && (cD == cC);
            u0 += eDA ? u3 : 0.f;  u1 += eDB ? u3 : 0.f;  u2 += eDC ? u3 : 0.f;
            u3 = (eDA || eDB || eDC) ? 0.f : u3;
        }

        const bool gr0 = (w0 != 0.f), gr1 = (w1 != 0.f);
        const bool gr2 = (w2 != 0.f), gr3 = (w3 != 0.f);
        const bool gc0 = (u0 != 0.f), gc1 = (u1 != 0.f);
        const bool gc2 = (u2 != 0.f), gc3 = (u3 != 0.f);

#define LD4(OFF) (*(const float4*)(fmb + (OFF)))
        // --- guarded loads, all issued before any use (MLP) ---
        const float4 f00 = (gr0 && gc0) ? LD4(rA + cA + cb) : z4;
        const float4 f01 = (gr0 && gc1) ? LD4(rA + cB + cb) : z4;
        const float4 f02 = (gr0 && gc2) ? LD4(rA + cC + cb) : z4;
        const float4 f03 = (gr0 && gc3) ? LD4(rA + cD + cb) : z4;
        const float4 f10 = (gr1 && gc0) ? LD4(rB + cA + cb) : z4;
        const float4 f11 = (gr1 && gc1) ? LD4(rB + cB + cb) : z4;
        const float4 f12 = (gr1 && gc2) ? LD4(rB + cC + cb) : z4;
        const float4 f13 = (gr1 && gc3) ? LD4(rB + cD + cb) : z4;
        const float4 f20 = (gr2 && gc0) ? LD4(rC + cA + cb) : z4;
        const float4 f21 = (gr2 && gc1) ? LD4(rC + cB + cb) : z4;
        const float4 f22 = (gr2 && gc2) ? LD4(rC + cC + cb) : z4;
        const float4 f23 = (gr2 && gc3) ? LD4(rC + cD + cb) : z4;
        const float4 f30 = (gr3 && gc0) ? LD4(rD + cA + cb) : z4;
        const float4 f31 = (gr3 && gc1) ? LD4(rD + cB + cb) : z4;
        const float4 f32 = (gr3 && gc2) ? LD4(rD + cC + cb) : z4;
        const float4 f33 = (gr3 && gc3) ? LD4(rD + cD + cb) : z4;
#undef LD4

        float4 acc = z4;
#define ACC4(Wt, F) { const float pw_ = (Wt); \
        acc.x = fmaf(pw_, (F).x, acc.x); acc.y = fmaf(pw_, (F).y, acc.y); \
        acc.z = fmaf(pw_, (F).z, acc.z); acc.w = fmaf(pw_, (F).w, acc.w); }
        ACC4(w0 * u0, f00); ACC4(w0 * u1, f01); ACC4(w0 * u2, f02); ACC4(w0 * u3, f03);
        ACC4(w1 * u0, f10); ACC4(w1 * u1, f11); ACC4(w1 * u2, f12); ACC4(w1 * u3, f13);
        ACC4(w2 * u0, f20); ACC4(w2 * u1, f21); ACC4(w2 * u2, f22); ACC4(w2 * u3, f23);
        ACC4(w3 * u0, f30); ACC4(w3 * u1, f31); ACC4(w3 * u2, f32); ACC4(w3 * u3, f33);
#undef ACC4

        // tile[bin][c], channel index XOR-swizzled by ((bin>>2)&7)<<2 so the
        // writeback's (c fixed, bin varying) reads spread across 8 banks.
        const unsigned xsw = (((unsigned)bin >> 2) & 7u) << 2;
        float* dst = &tile[bin * CCH + ((unsigned)(lane << 2) ^ xsw)];
        *(float4*)dst = make_float4(acc.x * 0.25f, acc.y * 0.25f,
                                    acc.z * 0.25f, acc.w * 0.25f);
    }

    __syncthreads();

    // ---- writeback: contiguous 256*49 floats, coalesced float4 stores ----
    float* oreg = out + (size_t)roi * (CCH * SS);
    for (int i = t; i < (CCH * SS) / 4; i += 512) {
        const int f0 = i * 4;
        float4 v;
        {
            const int f = f0 + 0;
            const int c = f / SS, bn = f - c * SS;
            v.x = tile[bn * CCH + (c ^ ((((unsigned)bn >> 2) & 7u) << 2))];
        }
        {
            const int f = f0 + 1;
            const int c = f / SS, bn = f - c * SS;
            v.y = tile[bn * CCH + (c ^ ((((unsigned)bn >> 2) & 7u) << 2))];
        }
        {
            const int f = f0 + 2;
            const int c = f / SS, bn = f - c * SS;
            v.z = tile[bn * CCH + (c ^ ((((unsigned)bn >> 2) & 7u) << 2))];
        }
        {
            const int f = f0 + 3;
            const int c = f / SS, bn = f - c * SS;
            v.w = tile[bn * CCH + (c ^ ((((unsigned)bn >> 2) & 7u) << 2))];
        }
        *(float4*)(oreg + f0) = v;
    }
}

extern "C" void kernel_launch(void* const* d_in, const int* in_sizes, int n_in,
                              void* d_out, int out_size, void* d_ws, size_t ws_size,
                              hipStream_t stream) {
    const float* fm2  = (const float*)d_in[0];
    const float* fm3  = (const float*)d_in[1];
    const float* fm4  = (const float*)d_in[2];
    const float* fm5  = (const float*)d_in[3];
    const float* rois = (const float*)d_in[4];
    float* out = (float*)d_out;

    roialign_kernel<<<BATCH * NROI, 512, 0, stream>>>(fm2, fm3, fm4, fm5, rois, out);
}

// Round 6
// 64.258 us; speedup vs baseline: 3.7697x; 3.7697x over previous
//
#include <hip/hip_runtime.h>

// ROIAlign (FPN, multi-level) for MI355X.
// Inputs (f32): fm2 [4,256,256,256] s4 | fm3 [4,128,128,256] s8
//               fm4 [4,64,64,256] s16  | fm5 [4,32,32,256] s32
//               rois [4,512,4] (x1,y1,x2,y2)
// Output (f32): [4,512,256,7,7]
//
// R5 -> R6: corner dedup done RIGHT. R5's per-lane `?:` load guards became
// an exec-mask saveexec chain (VGPR 48, VALUBusy 18%, 3.2x regression).
// Now: per-bin merged weights + 8-bit survive mask precomputed once per ROI
// (49 threads, LDS), hot loop reads mask via readfirstlane -> SGPR ->
// wave-uniform s_cbranch around each load. All loads issue before the FMA
// block (sched_barrier pin); skipped slots are zero so FMAs unconditional.

constexpr int S     = 7;
constexpr int SS    = 49;
constexpr int CCH   = 256;
constexpr int NROI  = 512;
constexpr int BATCH = 4;

__global__ __launch_bounds__(512, 4) void roialign_kernel(
    const float* __restrict__ fm2, const float* __restrict__ fm3,
    const float* __restrict__ fm4, const float* __restrict__ fm5,
    const float* __restrict__ rois, float* __restrict__ out)
{
    __shared__ float    tile[SS * CCH];   // 50176 B, XOR-swizzled channel index
    __shared__ float    s_wyh[14], s_wyl[14], s_wxh[14], s_wxl[14];
    __shared__ unsigned s_ry0[14], s_ry1[14], s_cx0[14], s_cx1[14];
    __shared__ float    s_bw[SS][4];      // merged row weights per bin
    __shared__ float    s_bu[SS][4];      // merged col weights per bin
    __shared__ unsigned s_bm[SS];         // survive mask: rows bits0-3, cols bits4-7

    const int roi = blockIdx.x;           // 0 .. B*N-1
    const int b   = roi >> 9;

    // ---- wave-uniform prologue ----
    const float x1  = rois[roi * 4 + 0];
    const float y1v = rois[roi * 4 + 1];
    const float x2  = rois[roi * 4 + 2];
    const float y2v = rois[roi * 4 + 3];

    const float area = (y2v - y1v) * (x2 - x1);
    const float lraw = logf(sqrtf(area) * (1.0f / 224.0f)) * 1.4426950408889634f + 4.0f;
    int lvl = (int)rintf(lraw);
    lvl = lvl < 2 ? 2 : (lvl > 5 ? 5 : lvl);

    const float* fm; int H; float scale;
    if (lvl == 2)      { fm = fm2; H = 256; scale = 0.25f;    }
    else if (lvl == 3) { fm = fm3; H = 128; scale = 0.125f;   }
    else if (lvl == 4) { fm = fm4; H = 64;  scale = 0.0625f;  }
    else               { fm = fm5; H = 32;  scale = 0.03125f; }
    const int W = H;
    fm += (size_t)b * H * W * CCH;

    const float bx1 = x1 * scale, by1 = y1v * scale;
    const float rw  = fmaxf(x2 * scale - bx1, 1.0f);
    const float rh  = fmaxf(y2v * scale - by1, 1.0f);
    const float stx = rw * (1.0f / 7.0f);
    const float sty = rh * (1.0f / 7.0f);

    const int t = threadIdx.x;

    // ---- sample LUT: 14 y entries (wave 0) + 14 x entries (wave 1) ----
    if (t < 14) {
        const int k = t;
        const float yy = by1 + ((float)k + 0.5f) * 0.5f * sty;
        const float Hf = (float)H;
        const bool  v  = (yy > -1.0f) && (yy < Hf);
        const float yc = fminf(fmaxf(yy, 0.0f), Hf - 1.0f);
        const int   y0 = (int)floorf(yc);
        const int   y1i = min(y0 + 1, H - 1);
        const float ly = yc - (float)y0;
        s_wyl[k] = v ? ly : 0.0f;
        s_wyh[k] = v ? 1.0f - ly : 0.0f;
        s_ry0[k] = (unsigned)(y0  * W * (CCH * 4));   // byte offset of fm row
        s_ry1[k] = (unsigned)(y1i * W * (CCH * 4));
    } else if (t >= 64 && t < 78) {
        const int k = t - 64;
        const float xx = bx1 + ((float)k + 0.5f) * 0.5f * stx;
        const float Wf = (float)W;
        const bool  v  = (xx > -1.0f) && (xx < Wf);
        const float xc = fminf(fmaxf(xx, 0.0f), Wf - 1.0f);
        const int   x0 = (int)floorf(xc);
        const int   x1i = min(x0 + 1, W - 1);
        const float lx = xc - (float)x0;
        s_wxl[k] = v ? lx : 0.0f;
        s_wxh[k] = v ? 1.0f - lx : 0.0f;
        s_cx0[k] = (unsigned)(x0  * (CCH * 4));       // byte offset of fm col
        s_cx1[k] = (unsigned)(x1i * (CCH * 4));
    }
    __syncthreads();

    // ---- per-bin merged weights + survive mask (one thread per bin) ----
    if (t < SS) {
        const int sy = t / 7, sx = t - sy * 7;
        const int ky = sy << 1, kx = sx << 1;

        float w0 = s_wyh[ky], w1 = s_wyl[ky], w2 = s_wyh[ky + 1], w3 = s_wyl[ky + 1];
        {
            const unsigned rA = s_ry0[ky], rB = s_ry1[ky];
            const unsigned rC = s_ry0[ky + 1], rD = s_ry1[ky + 1];
            const bool eBA = (rB == rA);
            if (eBA) { w0 += w1; w1 = 0.f; }
            const bool eCA = (rC == rA);
            const bool eCB = !eCA && (rC == rB);
            if (eCA) w0 += w2; else if (eCB) w1 += w2;
            if (eCA || eCB) w2 = 0.f;
            const bool eDA = (rD == rA);
            const bool eDB = !eDA && (rD == rB);
            const bool eDC = !eDA && !eDB && (rD == rC);
            if (eDA) w0 += w3; else if (eDB) w1 += w3; else if (eDC) w2 += w3;
            if (eDA || eDB || eDC) w3 = 0.f;
        }
        float u0 = s_wxh[kx], u1 = s_wxl[kx], u2 = s_wxh[kx + 1], u3 = s_wxl[kx + 1];
        {
            const unsigned cA = s_cx0[kx], cB = s_cx1[kx];
            const unsigned cC = s_cx0[kx + 1], cD = s_cx1[kx + 1];
            const bool eBA = (cB == cA);
            if (eBA) { u0 += u1; u1 = 0.f; }
            const bool eCA = (cC == cA);
            const bool eCB = !eCA && (cC == cB);
            if (eCA) u0 += u2; else if (eCB) u1 += u2;
            if (eCA || eCB) u2 = 0.f;
            const bool eDA = (cD == cA);
            const bool eDB = !eDA && (cD == cB);
            const bool eDC = !eDA && !eDB && (cD == cC);
            if (eDA) u0 += u3; else if (eDB) u1 += u3; else if (eDC) u2 += u3;
            if (eDA || eDB || eDC) u3 = 0.f;
        }
        s_bw[t][0] = w0; s_bw[t][1] = w1; s_bw[t][2] = w2; s_bw[t][3] = w3;
        s_bu[t][0] = u0; s_bu[t][1] = u1; s_bu[t][2] = u2; s_bu[t][3] = u3;
        s_bm[t] = (w0 != 0.f ? 0x01u : 0u) | (w1 != 0.f ? 0x02u : 0u)
                | (w2 != 0.f ? 0x04u : 0u) | (w3 != 0.f ? 0x08u : 0u)
                | (u0 != 0.f ? 0x10u : 0u) | (u1 != 0.f ? 0x20u : 0u)
                | (u2 != 0.f ? 0x40u : 0u) | (u3 != 0.f ? 0x80u : 0u);
    }
    __syncthreads();

    // ---- compute: one bin per wave-pass, 4 channels (float4) per lane ----
    const int lane = t & 63;
    const int wv   = t >> 6;                       // 0..7
    const unsigned cb = (unsigned)(lane << 4);     // byte offset within pixel

    const char* __restrict__ fmb = (const char*)fm;
    const float4 z4 = make_float4(0.f, 0.f, 0.f, 0.f);

    for (int bin = wv; bin < SS; bin += 8) {
        const int sy = bin / 7;
        const int sx = bin - sy * 7;
        const int ky = sy << 1, kx = sx << 1;

        // scalar survive mask -> wave-uniform s_cbranch guards
        const unsigned m = (unsigned)__builtin_amdgcn_readfirstlane((int)s_bm[bin]);

        const float w0 = s_bw[bin][0], w1 = s_bw[bin][1];
        const float w2 = s_bw[bin][2], w3 = s_bw[bin][3];
        const float u0 = s_bu[bin][0], u1 = s_bu[bin][1];
        const float u2 = s_bu[bin][2], u3 = s_bu[bin][3];

        const unsigned rA = s_ry0[ky],     rB = s_ry1[ky];
        const unsigned rC = s_ry0[ky + 1], rD = s_ry1[ky + 1];
        const unsigned cA = s_cx0[kx],     cB = s_cx1[kx];
        const unsigned cC = s_cx0[kx + 1], cD = s_cx1[kx + 1];

#define LD4(OFF) (*(const float4*)(fmb + (OFF)))
        float4 f00 = z4, f01 = z4, f02 = z4, f03 = z4;
        float4 f10 = z4, f11 = z4, f12 = z4, f13 = z4;
        float4 f20 = z4, f21 = z4, f22 = z4, f23 = z4;
        float4 f30 = z4, f31 = z4, f32 = z4, f33 = z4;

        if ((m & 0x11u) == 0x11u) f00 = LD4(rA + cA + cb);
        if ((m & 0x21u) == 0x21u) f01 = LD4(rA + cB + cb);
        if ((m & 0x41u) == 0x41u) f02 = LD4(rA + cC + cb);
        if ((m & 0x81u) == 0x81u) f03 = LD4(rA + cD + cb);
        if ((m & 0x12u) == 0x12u) f10 = LD4(rB + cA + cb);
        if ((m & 0x22u) == 0x22u) f11 = LD4(rB + cB + cb);
        if ((m & 0x42u) == 0x42u) f12 = LD4(rB + cC + cb);
        if ((m & 0x82u) == 0x82u) f13 = LD4(rB + cD + cb);
        if ((m & 0x14u) == 0x14u) f20 = LD4(rC + cA + cb);
        if ((m & 0x24u) == 0x24u) f21 = LD4(rC + cB + cb);
        if ((m & 0x44u) == 0x44u) f22 = LD4(rC + cC + cb);
        if ((m & 0x84u) == 0x84u) f23 = LD4(rC + cD + cb);
        if ((m & 0x18u) == 0x18u) f30 = LD4(rD + cA + cb);
        if ((m & 0x28u) == 0x28u) f31 = LD4(rD + cB + cb);
        if ((m & 0x48u) == 0x48u) f32 = LD4(rD + cC + cb);
        if ((m & 0x88u) == 0x88u) f33 = LD4(rD + cD + cb);
#undef LD4
        __builtin_amdgcn_sched_barrier(0);   // keep loads batched above FMAs

        float4 acc = z4;
#define ACC4(Wt, F) { const float pw_ = (Wt); \
        acc.x = fmaf(pw_, (F).x, acc.x); acc.y = fmaf(pw_, (F).y, acc.y); \
        acc.z = fmaf(pw_, (F).z, acc.z); acc.w = fmaf(pw_, (F).w, acc.w); }
        ACC4(w0 * u0, f00); ACC4(w0 * u1, f01); ACC4(w0 * u2, f02); ACC4(w0 * u3, f03);
        ACC4(w1 * u0, f10); ACC4(w1 * u1, f11); ACC4(w1 * u2, f12); ACC4(w1 * u3, f13);
        ACC4(w2 * u0, f20); ACC4(w2 * u1, f21); ACC4(w2 * u2, f22); ACC4(w2 * u3, f23);
        ACC4(w3 * u0, f30); ACC4(w3 * u1, f31); ACC4(w3 * u2, f32); ACC4(w3 * u3, f33);
#undef ACC4

        // tile[bin][c], channel index XOR-swizzled so the writeback's
        // (c fixed, bin varying) reads spread across banks.
        const unsigned xsw = (((unsigned)bin >> 2) & 7u) << 2;
        float* dst = &tile[bin * CCH + ((unsigned)(lane << 2) ^ xsw)];
        *(float4*)dst = make_float4(acc.x * 0.25f, acc.y * 0.25f,
                                    acc.z * 0.25f, acc.w * 0.25f);
    }

    __syncthreads();

    // ---- writeback: contiguous 256*49 floats, coalesced float4 stores ----
    float* oreg = out + (size_t)roi * (CCH * SS);
    for (int i = t; i < (CCH * SS) / 4; i += 512) {
        const int f0 = i * 4;
        float4 v;
        {
            const int f = f0 + 0;
            const int c = f / SS, bn = f - c * SS;
            v.x = tile[bn * CCH + (c ^ ((((unsigned)bn >> 2) & 7u) << 2))];
        }
        {
            const int f = f0 + 1;
            const int c = f / SS, bn = f - c * SS;
            v.y = tile[bn * CCH + (c ^ ((((unsigned)bn >> 2) & 7u) << 2))];
        }
        {
            const int f = f0 + 2;
            const int c = f / SS, bn = f - c * SS;
            v.z = tile[bn * CCH + (c ^ ((((unsigned)bn >> 2) & 7u) << 2))];
        }
        {
            const int f = f0 + 3;
            const int c = f / SS, bn = f - c * SS;
            v.w = tile[bn * CCH + (c ^ ((((unsigned)bn >> 2) & 7u) << 2))];
        }
        *(float4*)(oreg + f0) = v;
    }
}

extern "C" void kernel_launch(void* const* d_in, const int* in_sizes, int n_in,
                              void* d_out, int out_size, void* d_ws, size_t ws_size,
                              hipStream_t stream) {
    const float* fm2  = (const float*)d_in[0];
    const float* fm3  = (const float*)d_in[1];
    const float* fm4  = (const float*)d_in[2];
    const float* fm5  = (const float*)d_in[3];
    const float* rois = (const float*)d_in[4];
    float* out = (float*)d_out;

    roialign_kernel<<<BATCH * NROI, 512, 0, stream>>>(fm2, fm3, fm4, fm5, rois, out);
}